// Round 1
// baseline (45.598 us; speedup 1.0000x reference)
//
#include <hip/hip_runtime.h>

// 2-level 3D Haar DWT, fully fused.
// Input x: (4, 1, 128, 256, 256) f32.
// Output: [ ll2 (4,1,32,64,64) | yh1 (4,7,64,128,128) | yh2 (4,7,32,64,64) ]
// Channel order per level: c = 4*b_w + 2*b_h + b_d (W filtered first, then H, then D).
// lo = (x0+x1)/sqrt2, hi = (x0-x1)/sqrt2  -> 2x2x2 Hadamard scaled by 2^-1.5.

#define YH1_OFF 524288      // 4*1*32*64*64
#define YH2_OFF 29884416    // YH1_OFF + 4*7*64*128*128
#define S_HAAR3 0.35355339059327373f

__global__ __launch_bounds__(256) void dwt3d_haar_fused(
    const float* __restrict__ x, float* __restrict__ out)
{
    const int tid = blockIdx.x * 256 + threadIdx.x;
    const int w2 = tid & 63;          // level-2 W index (0..63)
    const int h2 = (tid >> 6) & 63;   // level-2 H index (0..63)
    const int d2 = (tid >> 12) & 31;  // level-2 D index (0..31)
    const int n  = tid >> 17;         // batch (0..3)

    // 4x4x4 input block base
    const float* xb = x + (((n * 128 + (d2 << 2)) * 256 + (h2 << 2)) * 256 + (w2 << 2));

    float v[4][4][4];
#pragma unroll
    for (int dz = 0; dz < 4; ++dz) {
#pragma unroll
        for (int hy = 0; hy < 4; ++hy) {
            const float4 r = *reinterpret_cast<const float4*>(xb + dz * 65536 + hy * 256);
            v[dz][hy][0] = r.x; v[dz][hy][1] = r.y;
            v[dz][hy][2] = r.z; v[dz][hy][3] = r.w;
        }
    }

    float ll1[2][2][2];  // level-1 LLL values (already scaled)

#pragma unroll
    for (int sd = 0; sd < 2; ++sd) {
#pragma unroll
        for (int sh = 0; sh < 2; ++sh) {
            float o[2][8];  // [sw][channel]
#pragma unroll
            for (int sw = 0; sw < 2; ++sw) {
                float tw[2][2][2];  // [dd][hh][bw]
#pragma unroll
                for (int dd = 0; dd < 2; ++dd) {
#pragma unroll
                    for (int hh = 0; hh < 2; ++hh) {
                        const float a0 = v[2*sd+dd][2*sh+hh][2*sw+0];
                        const float a1 = v[2*sd+dd][2*sh+hh][2*sw+1];
                        tw[dd][hh][0] = a0 + a1;
                        tw[dd][hh][1] = a0 - a1;
                    }
                }
                float th[2][2][2];  // [dd][bh][bw]
#pragma unroll
                for (int dd = 0; dd < 2; ++dd) {
#pragma unroll
                    for (int bw = 0; bw < 2; ++bw) {
                        th[dd][0][bw] = tw[dd][0][bw] + tw[dd][1][bw];
                        th[dd][1][bw] = tw[dd][0][bw] - tw[dd][1][bw];
                    }
                }
#pragma unroll
                for (int bh = 0; bh < 2; ++bh) {
#pragma unroll
                    for (int bw = 0; bw < 2; ++bw) {
                        o[sw][4*bw + 2*bh + 0] = S_HAAR3 * (th[0][bh][bw] + th[1][bh][bw]);
                        o[sw][4*bw + 2*bh + 1] = S_HAAR3 * (th[0][bh][bw] - th[1][bh][bw]);
                    }
                }
                ll1[sd][sh][sw] = o[sw][0];
            }
            // yh1 writes: channels 1..7, contiguous w-pair -> float2
            const int d1 = 2*d2 + sd;
            const int h1 = 2*h2 + sh;
            const int wbase = YH1_OFF + (((n * 7) * 64 + d1) * 128 + h1) * 128 + 2*w2;
#pragma unroll
            for (int c = 1; c < 8; ++c) {
                float2 p;
                p.x = o[0][c];
                p.y = o[1][c];
                *reinterpret_cast<float2*>(out + wbase + (c - 1) * 1048576) = p;
            }
        }
    }

    // ---- level 2 on the 2x2x2 LLL block ----
    float tw[2][2][2];
#pragma unroll
    for (int dd = 0; dd < 2; ++dd) {
#pragma unroll
        for (int hh = 0; hh < 2; ++hh) {
            const float a0 = ll1[dd][hh][0];
            const float a1 = ll1[dd][hh][1];
            tw[dd][hh][0] = a0 + a1;
            tw[dd][hh][1] = a0 - a1;
        }
    }
    float th[2][2][2];
#pragma unroll
    for (int dd = 0; dd < 2; ++dd) {
#pragma unroll
        for (int bw = 0; bw < 2; ++bw) {
            th[dd][0][bw] = tw[dd][0][bw] + tw[dd][1][bw];
            th[dd][1][bw] = tw[dd][0][bw] - tw[dd][1][bw];
        }
    }
    float o2[8];
#pragma unroll
    for (int bh = 0; bh < 2; ++bh) {
#pragma unroll
        for (int bw = 0; bw < 2; ++bw) {
            o2[4*bw + 2*bh + 0] = S_HAAR3 * (th[0][bh][bw] + th[1][bh][bw]);
            o2[4*bw + 2*bh + 1] = S_HAAR3 * (th[0][bh][bw] - th[1][bh][bw]);
        }
    }

    // ll2
    out[((n * 32 + d2) * 64 + h2) * 64 + w2] = o2[0];
    // yh2
    const int y2base = YH2_OFF + (((n * 7) * 32 + d2) * 64 + h2) * 64 + w2;
#pragma unroll
    for (int c = 1; c < 8; ++c) {
        out[y2base + (c - 1) * 131072] = o2[c];
    }
}

extern "C" void kernel_launch(void* const* d_in, const int* in_sizes, int n_in,
                              void* d_out, int out_size, void* d_ws, size_t ws_size,
                              hipStream_t stream) {
    const float* x = (const float*)d_in[0];
    float* out = (float*)d_out;
    // total output voxels at level 2: 4 * 32 * 64 * 64 = 524288 threads
    dwt3d_haar_fused<<<2048, 256, 0, stream>>>(x, out);
}

// Round 3
// 45.247 us; speedup vs baseline: 1.0078x; 1.0078x over previous
//
#include <hip/hip_runtime.h>

// 2-level 3D Haar DWT, fully fused, non-temporal output stores.
// Input x: (4, 1, 128, 256, 256) f32.
// Output: [ ll2 (4,1,32,64,64) | yh1 (4,7,64,128,128) | yh2 (4,7,32,64,64) ]
// Channel order per level: c = 4*b_w + 2*b_h + b_d (W filtered first, then H, then D).
// lo = (x0+x1)/sqrt2, hi = (x0-x1)/sqrt2  -> 2x2x2 Hadamard scaled by 2^-1.5.
//
// R3: R2's nontemporal-store idea, fixed for compile — the builtin needs a
// native clang vector type, not HIP_vector_type<float,2>.

#define YH1_OFF 524288      // 4*1*32*64*64
#define YH2_OFF 29884416    // YH1_OFF + 4*7*64*128*128
#define S_HAAR3 0.35355339059327373f

typedef float f32x2 __attribute__((ext_vector_type(2)));

__global__ __launch_bounds__(256) void dwt3d_haar_fused(
    const float* __restrict__ x, float* __restrict__ out)
{
    const int tid = blockIdx.x * 256 + threadIdx.x;
    const int w2 = tid & 63;          // level-2 W index (0..63)
    const int h2 = (tid >> 6) & 63;   // level-2 H index (0..63)
    const int d2 = (tid >> 12) & 31;  // level-2 D index (0..31)
    const int n  = tid >> 17;         // batch (0..3)

    // 4x4x4 input block base
    const float* xb = x + (((n * 128 + (d2 << 2)) * 256 + (h2 << 2)) * 256 + (w2 << 2));

    float v[4][4][4];
#pragma unroll
    for (int dz = 0; dz < 4; ++dz) {
#pragma unroll
        for (int hy = 0; hy < 4; ++hy) {
            const float4 r = *reinterpret_cast<const float4*>(xb + dz * 65536 + hy * 256);
            v[dz][hy][0] = r.x; v[dz][hy][1] = r.y;
            v[dz][hy][2] = r.z; v[dz][hy][3] = r.w;
        }
    }

    float ll1[2][2][2];  // level-1 LLL values (already scaled)

#pragma unroll
    for (int sd = 0; sd < 2; ++sd) {
#pragma unroll
        for (int sh = 0; sh < 2; ++sh) {
            float o[2][8];  // [sw][channel]
#pragma unroll
            for (int sw = 0; sw < 2; ++sw) {
                float tw[2][2][2];  // [dd][hh][bw]
#pragma unroll
                for (int dd = 0; dd < 2; ++dd) {
#pragma unroll
                    for (int hh = 0; hh < 2; ++hh) {
                        const float a0 = v[2*sd+dd][2*sh+hh][2*sw+0];
                        const float a1 = v[2*sd+dd][2*sh+hh][2*sw+1];
                        tw[dd][hh][0] = a0 + a1;
                        tw[dd][hh][1] = a0 - a1;
                    }
                }
                float th[2][2][2];  // [dd][bh][bw]
#pragma unroll
                for (int dd = 0; dd < 2; ++dd) {
#pragma unroll
                    for (int bw = 0; bw < 2; ++bw) {
                        th[dd][0][bw] = tw[dd][0][bw] + tw[dd][1][bw];
                        th[dd][1][bw] = tw[dd][0][bw] - tw[dd][1][bw];
                    }
                }
#pragma unroll
                for (int bh = 0; bh < 2; ++bh) {
#pragma unroll
                    for (int bw = 0; bw < 2; ++bw) {
                        o[sw][4*bw + 2*bh + 0] = S_HAAR3 * (th[0][bh][bw] + th[1][bh][bw]);
                        o[sw][4*bw + 2*bh + 1] = S_HAAR3 * (th[0][bh][bw] - th[1][bh][bw]);
                    }
                }
                ll1[sd][sh][sw] = o[sw][0];
            }
            // yh1 writes: channels 1..7, contiguous w-pair -> dwordx2 nt store
            const int d1 = 2*d2 + sd;
            const int h1 = 2*h2 + sh;
            const int wbase = YH1_OFF + (((n * 7) * 64 + d1) * 128 + h1) * 128 + 2*w2;
#pragma unroll
            for (int c = 1; c < 8; ++c) {
                f32x2 p;
                p.x = o[0][c];
                p.y = o[1][c];
                __builtin_nontemporal_store(
                    p, reinterpret_cast<f32x2*>(out + wbase + (c - 1) * 1048576));
            }
        }
    }

    // ---- level 2 on the 2x2x2 LLL block ----
    float tw[2][2][2];
#pragma unroll
    for (int dd = 0; dd < 2; ++dd) {
#pragma unroll
        for (int hh = 0; hh < 2; ++hh) {
            const float a0 = ll1[dd][hh][0];
            const float a1 = ll1[dd][hh][1];
            tw[dd][hh][0] = a0 + a1;
            tw[dd][hh][1] = a0 - a1;
        }
    }
    float th[2][2][2];
#pragma unroll
    for (int dd = 0; dd < 2; ++dd) {
#pragma unroll
        for (int bw = 0; bw < 2; ++bw) {
            th[dd][0][bw] = tw[dd][0][bw] + tw[dd][1][bw];
            th[dd][1][bw] = tw[dd][0][bw] - tw[dd][1][bw];
        }
    }
    float o2[8];
#pragma unroll
    for (int bh = 0; bh < 2; ++bh) {
#pragma unroll
        for (int bw = 0; bw < 2; ++bw) {
            o2[4*bw + 2*bh + 0] = S_HAAR3 * (th[0][bh][bw] + th[1][bh][bw]);
            o2[4*bw + 2*bh + 1] = S_HAAR3 * (th[0][bh][bw] - th[1][bh][bw]);
        }
    }

    // ll2 (non-temporal)
    __builtin_nontemporal_store(o2[0], out + ((n * 32 + d2) * 64 + h2) * 64 + w2);
    // yh2 (non-temporal)
    const int y2base = YH2_OFF + (((n * 7) * 32 + d2) * 64 + h2) * 64 + w2;
#pragma unroll
    for (int c = 1; c < 8; ++c) {
        __builtin_nontemporal_store(o2[c], out + y2base + (c - 1) * 131072);
    }
}

extern "C" void kernel_launch(void* const* d_in, const int* in_sizes, int n_in,
                              void* d_out, int out_size, void* d_ws, size_t ws_size,
                              hipStream_t stream) {
    const float* x = (const float*)d_in[0];
    float* out = (float*)d_out;
    // total output voxels at level 2: 4 * 32 * 64 * 64 = 524288 threads
    dwt3d_haar_fused<<<2048, 256, 0, stream>>>(x, out);
}

// Round 4
// 44.740 us; speedup vs baseline: 1.0192x; 1.0114x over previous
//
#include <hip/hip_runtime.h>

// 2-level 3D Haar DWT, fully fused; output stores via inline-asm
// global_store with "sc0 sc1 nt" to bypass L2+Infinity-Cache allocation
// (R3 showed __builtin_nontemporal_store's plain `nt` did NOT stop the
// write stream from evicting half the input from L3: FETCH stuck at 65.5MB).
//
// Input x: (4, 1, 128, 256, 256) f32.
// Output: [ ll2 (4,1,32,64,64) | yh1 (4,7,64,128,128) | yh2 (4,7,32,64,64) ]
// Channel order per level: c = 4*b_w + 2*b_h + b_d (W filtered first, then H, then D).
// lo = (x0+x1)/sqrt2, hi = (x0-x1)/sqrt2  -> 2x2x2 Hadamard scaled by 2^-1.5.

#define YH1_OFF 524288      // 4*1*32*64*64
#define YH2_OFF 29884416    // YH1_OFF + 4*7*64*128*128
#define S_HAAR3 0.35355339059327373f

typedef float f32x2 __attribute__((ext_vector_type(2)));

__device__ __forceinline__ void store_stream_x2(float* addr, f32x2 v) {
    asm volatile("global_store_dwordx2 %0, %1, off sc0 sc1 nt"
                 :: "v"(addr), "v"(v) : "memory");
}
__device__ __forceinline__ void store_stream_x1(float* addr, float v) {
    asm volatile("global_store_dword %0, %1, off sc0 sc1 nt"
                 :: "v"(addr), "v"(v) : "memory");
}

__global__ __launch_bounds__(256) void dwt3d_haar_fused(
    const float* __restrict__ x, float* __restrict__ out)
{
    const int tid = blockIdx.x * 256 + threadIdx.x;
    const int w2 = tid & 63;          // level-2 W index (0..63)
    const int h2 = (tid >> 6) & 63;   // level-2 H index (0..63)
    const int d2 = (tid >> 12) & 31;  // level-2 D index (0..31)
    const int n  = tid >> 17;         // batch (0..3)

    // 4x4x4 input block base
    const float* xb = x + (((n * 128 + (d2 << 2)) * 256 + (h2 << 2)) * 256 + (w2 << 2));

    float v[4][4][4];
#pragma unroll
    for (int dz = 0; dz < 4; ++dz) {
#pragma unroll
        for (int hy = 0; hy < 4; ++hy) {
            const float4 r = *reinterpret_cast<const float4*>(xb + dz * 65536 + hy * 256);
            v[dz][hy][0] = r.x; v[dz][hy][1] = r.y;
            v[dz][hy][2] = r.z; v[dz][hy][3] = r.w;
        }
    }

    float ll1[2][2][2];  // level-1 LLL values (already scaled)

#pragma unroll
    for (int sd = 0; sd < 2; ++sd) {
#pragma unroll
        for (int sh = 0; sh < 2; ++sh) {
            float o[2][8];  // [sw][channel]
#pragma unroll
            for (int sw = 0; sw < 2; ++sw) {
                float tw[2][2][2];  // [dd][hh][bw]
#pragma unroll
                for (int dd = 0; dd < 2; ++dd) {
#pragma unroll
                    for (int hh = 0; hh < 2; ++hh) {
                        const float a0 = v[2*sd+dd][2*sh+hh][2*sw+0];
                        const float a1 = v[2*sd+dd][2*sh+hh][2*sw+1];
                        tw[dd][hh][0] = a0 + a1;
                        tw[dd][hh][1] = a0 - a1;
                    }
                }
                float th[2][2][2];  // [dd][bh][bw]
#pragma unroll
                for (int dd = 0; dd < 2; ++dd) {
#pragma unroll
                    for (int bw = 0; bw < 2; ++bw) {
                        th[dd][0][bw] = tw[dd][0][bw] + tw[dd][1][bw];
                        th[dd][1][bw] = tw[dd][0][bw] - tw[dd][1][bw];
                    }
                }
#pragma unroll
                for (int bh = 0; bh < 2; ++bh) {
#pragma unroll
                    for (int bw = 0; bw < 2; ++bw) {
                        o[sw][4*bw + 2*bh + 0] = S_HAAR3 * (th[0][bh][bw] + th[1][bh][bw]);
                        o[sw][4*bw + 2*bh + 1] = S_HAAR3 * (th[0][bh][bw] - th[1][bh][bw]);
                    }
                }
                ll1[sd][sh][sw] = o[sw][0];
            }
            // yh1 writes: channels 1..7, contiguous w-pair -> streaming dwordx2
            const int d1 = 2*d2 + sd;
            const int h1 = 2*h2 + sh;
            const int wbase = YH1_OFF + (((n * 7) * 64 + d1) * 128 + h1) * 128 + 2*w2;
#pragma unroll
            for (int c = 1; c < 8; ++c) {
                f32x2 p;
                p.x = o[0][c];
                p.y = o[1][c];
                store_stream_x2(out + wbase + (c - 1) * 1048576, p);
            }
        }
    }

    // ---- level 2 on the 2x2x2 LLL block ----
    float tw[2][2][2];
#pragma unroll
    for (int dd = 0; dd < 2; ++dd) {
#pragma unroll
        for (int hh = 0; hh < 2; ++hh) {
            const float a0 = ll1[dd][hh][0];
            const float a1 = ll1[dd][hh][1];
            tw[dd][hh][0] = a0 + a1;
            tw[dd][hh][1] = a0 - a1;
        }
    }
    float th[2][2][2];
#pragma unroll
    for (int dd = 0; dd < 2; ++dd) {
#pragma unroll
        for (int bw = 0; bw < 2; ++bw) {
            th[dd][0][bw] = tw[dd][0][bw] + tw[dd][1][bw];
            th[dd][1][bw] = tw[dd][0][bw] - tw[dd][1][bw];
        }
    }
    float o2[8];
#pragma unroll
    for (int bh = 0; bh < 2; ++bh) {
#pragma unroll
        for (int bw = 0; bw < 2; ++bw) {
            o2[4*bw + 2*bh + 0] = S_HAAR3 * (th[0][bh][bw] + th[1][bh][bw]);
            o2[4*bw + 2*bh + 1] = S_HAAR3 * (th[0][bh][bw] - th[1][bh][bw]);
        }
    }

    // ll2 (streaming)
    store_stream_x1(out + ((n * 32 + d2) * 64 + h2) * 64 + w2, o2[0]);
    // yh2 (streaming)
    const int y2base = YH2_OFF + (((n * 7) * 32 + d2) * 64 + h2) * 64 + w2;
#pragma unroll
    for (int c = 1; c < 8; ++c) {
        store_stream_x1(out + y2base + (c - 1) * 131072, o2[c]);
    }
}

extern "C" void kernel_launch(void* const* d_in, const int* in_sizes, int n_in,
                              void* d_out, int out_size, void* d_ws, size_t ws_size,
                              hipStream_t stream) {
    const float* x = (const float*)d_in[0];
    float* out = (float*)d_out;
    // total output voxels at level 2: 4 * 32 * 64 * 64 = 524288 threads
    dwt3d_haar_fused<<<2048, 256, 0, stream>>>(x, out);
}